// Round 8
// baseline (524.363 us; speedup 1.0000x reference)
//
#include <hip/hip_runtime.h>

// ---------------------------------------------------------------------------
// Fused 2-layer LSTM, N=8192, T=28, I=28, H=128, + final [128->10] linear.
// One block = 32 samples through all 28 timesteps of both layers.
// grid = 256 blocks x 1024 threads (16 waves) -> 1 block / CU, 4 waves/SIMD.
//
// R8 = R7 (passing, 157.5us) with 2x the waves at constant total work.
// rocprof R7: VALUBusy 46 / MfmaUtil 26 / HBM 1.6% / Occupancy 22% (2
// waves/SIMD) -> busy-sum ~65%, rest is dependency/barrier stall that 2
// waves/SIMD cannot hide.  Split each R7 wave in two: wave -> (wavem =
// sample half of 16, waved = 16-dim group).  Per-wave MFMA/VALU/trans work
// halves, wave count doubles -> same per-SIMD totals with 2x latency-hiding.
// Bonus: per-thread reg demand drops ~135 -> ~110 <= 128 (acc 32->16,
// c 16->8), killing the ~7-reg/thread residual spill (R7 WRITE_SIZE 3.9MB).
//
// Structure (R6/R7, verified): 2 barriers/timestep, h0 double-buffered in
// LDS (h0_t write needs no pre-barrier: buf[t&1]'s previous readers --
// L1(t-2), L0(t-1) -- completed before BarB(t-1)).  Schedule per t:
//     L0: read x_t + h0_{t-1}[(t-1)&1] -> MFMA -> acts -> write h0_t[t&1]
//     BarA: h0_t visible
//     L1: stage_x(t+1) early; read h0_t + h1_{t-1} -> MFMA -> acts -> hb
//     BarB: h1_{t-1} reads done; x_{t+1} visible for t+1
//     write h1_t
// Activations use v_rcp_f32 (R7): 1-ULP rcp vs ~8-inst IEEE divide.
// LDS: wih1 131072 + h0 2x8192 + h1 8192 + x 2048 = 157696 <= 163840.
// ---------------------------------------------------------------------------

typedef short  short8   __attribute__((ext_vector_type(8)));
typedef float  float4_t __attribute__((ext_vector_type(4)));

#define WIH1_OFF 0        // 131072 B : w_ih1, persistent in LDS
#define H0_OFF   131072   // 2 x 8192 B : h0 double buffer
#define H1_OFF   147456   //     8192 B : h1 single buffer
#define X_OFF    155648   //     2048 B : x_t tile (k padded 28->32, zeros)
#define SMEM_SZ  157696

__device__ __forceinline__ unsigned short bf16r(float v) {
  union { float f; unsigned u; } x; x.f = v;
  unsigned r = x.u + 0x7fffu + ((x.u >> 16) & 1u);   // round-to-nearest-even
  return (unsigned short)(r >> 16);
}
__device__ __forceinline__ float bf2f(unsigned short b) {
  union { unsigned u; float f; } x; x.u = ((unsigned)b) << 16;
  return x.f;
}
// v_rcp_f32-based activations (1 ULP; negligible vs bf16 quantum).
__device__ __forceinline__ float sigf(float x) {
  return __builtin_amdgcn_rcpf(1.0f + __expf(-x));
}
__device__ __forceinline__ float tanhfast(float x) {
  return 1.0f - 2.0f * __builtin_amdgcn_rcpf(__expf(2.0f * x) + 1.0f);
}

// ---------------------------------------------------------------------------
// Prologue: pack weights (fp32 -> bf16) into MFMA B-frag tiled layout in ws.
// ws (unsigned short units):
//   [0      ,16384) : w_ih0  [1 kc][32 tiles][64 lanes][8]  (k padded to 32)
//   [16384  ,81920) : w_hh0  [4 kc][32 tiles][64][8]
//   [81920 ,147456) : w_ih1  [4 kc][32][64][8]
//   [147456,212992) : w_hh1  [4 kc][32][64][8]
// element (tile,lane,j): row = tile*16 + (lane&15), k = kc*32 + (lane>>4)*8 + j
// ---------------------------------------------------------------------------
__global__ void pack_weights(const float* __restrict__ wih0, const float* __restrict__ whh0,
                             const float* __restrict__ wih1, const float* __restrict__ whh1,
                             unsigned short* __restrict__ dst)
{
  int e = blockIdx.x * 256 + threadIdx.x;
  const float* src; int K; int i;
  if      (e < 16384)  { src = wih0; K = 28;  i = e;          }
  else if (e < 81920)  { src = whh0; K = 128; i = e - 16384;  }
  else if (e < 147456) { src = wih1; K = 128; i = e - 81920;  }
  else if (e < 212992) { src = whh1; K = 128; i = e - 147456; }
  else return;
  int j = i & 7, lane = (i >> 3) & 63, tile = (i >> 9) & 31, kc = i >> 14;
  int row = tile * 16 + (lane & 15);
  int k = kc * 32 + ((lane >> 4) << 3) + j;
  float v = (k < K) ? src[row * K + k] : 0.0f;
  dst[e] = bf16r(v);
}

// ---------------------------------------------------------------------------
// Main fused kernel.  16 waves: wavem = wave&1 (sample half of 16),
// waved = wave>>1 (owns h-dims [waved*16, waved*16+16)).
// ---------------------------------------------------------------------------
__global__ __launch_bounds__(1024, 4)
void lstm_fused(const float* __restrict__ xg,
                const unsigned short* __restrict__ wpack,
                const float* __restrict__ bih0, const float* __restrict__ bhh0,
                const float* __restrict__ bih1, const float* __restrict__ bhh1,
                const float* __restrict__ wout, const float* __restrict__ bout,
                float* __restrict__ out)
{
  __shared__ __align__(16) char smem[SMEM_SZ];

  const int tid   = threadIdx.x;
  const int lane  = tid & 63;
  const int wave  = tid >> 6;         // 0..15
  const int wavem = wave & 1;         // sample-half (replaces the mt loop)
  const int waved = wave >> 1;        // dim group 0..7
  const int q     = lane >> 4;        // quad: acc rows q*4 .. q*4+3
  const int mcol  = lane & 15;        // acc col = h-dim within dim group
  const int n0    = blockIdx.x * 32;  // batch tile base

  const short8* wp = (const short8*)wpack;

  // ---- persistent weight fragments in registers (indexed by waved) -------
  short8 wih0[4], whh0[4][4], whh1[4][4];          // [g] / [kc][g]
#pragma unroll
  for (int g = 0; g < 4; ++g)
    wih0[g] = wp[(g * 8 + waved) * 64 + lane];
#pragma unroll
  for (int kc = 0; kc < 4; ++kc)
#pragma unroll
    for (int g = 0; g < 4; ++g) {
      whh0[kc][g] = wp[ 2048 + (kc * 32 + g * 8 + waved) * 64 + lane];
      whh1[kc][g] = wp[18432 + (kc * 32 + g * 8 + waved) * 64 + lane];
    }

  // ---- persistent w_ih1 in LDS (131072 B; 8192 short8 / 1024 threads) ----
  {
    short8* dstp = (short8*)smem;
#pragma unroll
    for (int rr = 0; rr < 8; ++rr)
      dstp[rr * 1024 + tid] = wp[10240 + rr * 1024 + tid];
  }

  // ---- biases (per-lane, gate g, dim = waved*16+mcol) --------------------
  float bias0[4], bias1[4];
  {
    const int d = waved * 16 + mcol;
#pragma unroll
    for (int g = 0; g < 4; ++g) {
      bias0[g] = bih0[g * 128 + d] + bhh0[g * 128 + d];
      bias1[g] = bih1[g * 128 + d] + bhh1[g * 128 + d];
    }
  }

  // ---- zero h0 read-buffer (B half), h1, and x pad region ---------------
  {
    int* z0 = (int*)(smem + H0_OFF + 8192);   // h0 buf1 (read as h0_{-1})
    int* z1 = (int*)(smem + H1_OFF);          // h1
#pragma unroll
    for (int rr = 0; rr < 2; ++rr) { z0[rr * 1024 + tid] = 0; z1[rr * 1024 + tid] = 0; }
    if (tid < 512) ((int*)(smem + X_OFF))[tid] = 0;   // x tile incl. k pad
  }

  // ---- x_t staging: fp32 global -> bf16 A-frag tile in LDS ---------------
  auto stage_x = [&](int t) {
    if (tid < 448) {
      int s  = tid / 14;
      int kk = tid - s * 14;
      int k  = kk * 2;
      const float* xs = xg + (size_t)(n0 + s) * 784 + t * 28 + k;
      float v0 = xs[0], v1 = xs[1];
      unsigned u = (unsigned)bf16r(v0) | ((unsigned)bf16r(v1) << 16);
      int mt = s >> 4;
      int addr = X_OFF + mt * 1024 + ((((k >> 3) & 3) << 4) + (s & 15)) * 16 + (k & 7) * 2;
      *(unsigned*)(smem + addr) = u;
    }
  };
  stage_x(0);
  __syncthreads();   // weights in LDS, x_0 staged, h zeroed

  const short8* Xf  = (const short8*)(smem + X_OFF);
  const short8* W1f = (const short8*)(smem + WIH1_OFF);
  const short8* H1f = (const short8*)(smem + H1_OFF);

  // per-lane constant part of the h-write address (A-frag tiled position of
  // element (s, d) with d = waved*16+mcol):
  const int kc_d   = waved >> 1;
  const int sub    = ((waved & 1) << 1) | (mcol >> 3);
  const int hconst = kc_d * 1024 + sub * 256 + q * 64 + (mcol & 7) * 2;

  int h0r = H0_OFF + 8192, h0w = H0_OFF;   // t=0: read zeros (buf1), write buf0

  float c0[4] = {0.f, 0.f, 0.f, 0.f};
  float c1[4] = {0.f, 0.f, 0.f, 0.f};

#pragma unroll 1
  for (int t = 0; t < 28; ++t) {
    float4_t acc[4];
    unsigned short hb[4];

    // ================= LAYER 0 : gates = b0 + x_t@Wih0^T + h0@Whh0^T =====
#pragma unroll
    for (int g = 0; g < 4; ++g)
      acc[g] = (float4_t){bias0[g], bias0[g], bias0[g], bias0[g]};
    {
      short8 xf = Xf[wavem * 64 + lane];
#pragma unroll
      for (int g = 0; g < 4; ++g)
        acc[g] = __builtin_amdgcn_mfma_f32_16x16x32_bf16(xf, wih0[g], acc[g], 0, 0, 0);
    }
    {
      const short8* H0R = (const short8*)(smem + h0r);
#pragma unroll
      for (int kc = 0; kc < 4; ++kc) {
        short8 hf = H0R[(wavem * 4 + kc) * 64 + lane];
#pragma unroll
        for (int g = 0; g < 4; ++g)
          acc[g] = __builtin_amdgcn_mfma_f32_16x16x32_bf16(hf, whh0[kc][g], acc[g], 0, 0, 0);
      }
    }
    // activations (gate order i,f,g,o); c stays in registers.  h0_t written
    // DIRECTLY to buf[t&1]: that buffer's previous readers (L1(t-2), L0(t-1))
    // all completed before BarB(t-1) -> no pre-write barrier needed.
#pragma unroll
    for (int r = 0; r < 4; ++r) {
      float c = sigf(acc[1][r]) * c0[r] + sigf(acc[0][r]) * tanhfast(acc[2][r]);
      c0[r] = c;
      *(unsigned short*)(smem + h0w + wavem * 4096 + r * 16 + hconst) =
          bf16r(sigf(acc[3][r]) * tanhfast(c));
    }

    __syncthreads();   // BarA: h0_t visible to all waves

    // stage x_{t+1} EARLY: full L1 phase of global-load latency cover
    // before BarB's vmcnt drain.  Visible to L0(t+1) after BarB.
    if (t < 27) stage_x(t + 1);

    // ================= LAYER 1 : gates = b1 + h0_t@Wih1^T + h1@Whh1^T ====
#pragma unroll
    for (int g = 0; g < 4; ++g)
      acc[g] = (float4_t){bias1[g], bias1[g], bias1[g], bias1[g]};
    {
      const short8* H0W = (const short8*)(smem + h0w);
#pragma unroll
      for (int kc = 0; kc < 4; ++kc) {
        short8 wf[4];
#pragma unroll
        for (int g = 0; g < 4; ++g)
          wf[g] = W1f[(kc * 32 + g * 8 + waved) * 64 + lane];
        short8 hf = H0W[(wavem * 4 + kc) * 64 + lane];
#pragma unroll
        for (int g = 0; g < 4; ++g)
          acc[g] = __builtin_amdgcn_mfma_f32_16x16x32_bf16(hf, wf[g], acc[g], 0, 0, 0);
      }
#pragma unroll
      for (int kc = 0; kc < 4; ++kc) {
        short8 hf = H1f[(wavem * 4 + kc) * 64 + lane];
#pragma unroll
        for (int g = 0; g < 4; ++g)
          acc[g] = __builtin_amdgcn_mfma_f32_16x16x32_bf16(hf, whh1[kc][g], acc[g], 0, 0, 0);
      }
    }
    // activations -> hb regs (h1 write must wait for BarB: single buffer)
#pragma unroll
    for (int r = 0; r < 4; ++r) {
      float c = sigf(acc[1][r]) * c1[r] + sigf(acc[0][r]) * tanhfast(acc[2][r]);
      c1[r] = c;
      hb[r] = bf16r(sigf(acc[3][r]) * tanhfast(c));
    }

    __syncthreads();   // BarB: all h1_{t-1} reads done; x_{t+1} visible next

#pragma unroll
    for (int r = 0; r < 4; ++r)
      *(unsigned short*)(smem + H1_OFF + wavem * 4096 + r * 16 + hconst) = hb[r];

    h0r ^= 8192; h0w ^= 8192;
  }
  __syncthreads();     // final h1 visible for epilogue

  // ================= epilogue: out[s][o] = h1 . wout[o] + bout[o] =========
  if (tid < 320) {
    int s = tid / 10, o = tid - (tid / 10) * 10;
    float sum = bout[o];
#pragma unroll
    for (int kc = 0; kc < 4; ++kc)
#pragma unroll
      for (int sb = 0; sb < 4; ++sb) {
        short8 hv = H1f[((s >> 4) * 4 + kc) * 64 + sb * 16 + (s & 15)];
        int dbase = kc * 32 + sb * 8;
        float4_t w0 = *(const float4_t*)(wout + o * 128 + dbase);
        float4_t w1 = *(const float4_t*)(wout + o * 128 + dbase + 4);
#pragma unroll
        for (int j = 0; j < 4; ++j) {
          sum += bf2f((unsigned short)hv[j])     * w0[j];
          sum += bf2f((unsigned short)hv[j + 4]) * w1[j];
        }
      }
    out[(size_t)(n0 + s) * 10 + o] = sum;
  }
}

extern "C" void kernel_launch(void* const* d_in, const int* in_sizes, int n_in,
                              void* d_out, int out_size, void* d_ws, size_t ws_size,
                              hipStream_t stream) {
  const float* x    = (const float*)d_in[0];
  const float* wih0 = (const float*)d_in[1];
  const float* whh0 = (const float*)d_in[2];
  const float* bih0 = (const float*)d_in[3];
  const float* bhh0 = (const float*)d_in[4];
  const float* wih1 = (const float*)d_in[5];
  const float* whh1 = (const float*)d_in[6];
  const float* bih1 = (const float*)d_in[7];
  const float* bhh1 = (const float*)d_in[8];
  const float* wout = (const float*)d_in[9];
  const float* bout = (const float*)d_in[10];

  unsigned short* wp = (unsigned short*)d_ws;   // 425984 B used

  pack_weights<<<832, 256, 0, stream>>>(wih0, whh0, wih1, whh1, wp);
  lstm_fused<<<256, 1024, 0, stream>>>(x, wp, bih0, bhh0, bih1, bhh1, wout, bout,
                                       (float*)d_out);
}

// Round 9
// 215.330 us; speedup vs baseline: 2.4352x; 2.4352x over previous
//
#include <hip/hip_runtime.h>

// ---------------------------------------------------------------------------
// Fused 2-layer LSTM, N=8192, T=28, I=28, H=128, + final [128->10] linear.
// One block = 32 samples through all 28 timesteps of both layers.
// grid = 256 blocks x 512 threads (8 waves) -> 1 block/CU, 2 waves/SIMD.
//
// R9 = R7 (passing, 157.5us) restructured to ONE barrier per timestep.
// R8 lesson: persistent-register weights (144 VGPR/wave) cap the kernel at
// 2 waves/SIMD (256 regs/wave); 4 waves/SIMD -> 128-reg cap -> 1.5GB of
// scratch traffic.  So we stay at 8 waves and cut sync cost instead:
//   - h0 AND h1 double-buffered: LDS = wih1 131072 + 16384 + 16384 = 163840
//     (exactly the gfx950 max).  One __syncthreads()/t is then race-free:
//       interval [Bar(t),Bar(t+1)] runs {L1(t); L0(t+1)}:
//       * L0(t+1) writes h0[(t+1)&1]: prev readers L1(t-1),L0(t) ran in
//         earlier intervals (sep. by Bar(t)).  L1(t) reads h0[t&1] ✓ diff buf.
//       * L1(t) writes h1[t&1]: prev reader L1(t-1) in earlier interval ✓.
//       * L1(t) reads h1[(t-1)&1] written by L1(t-1), visible via Bar(t) ✓.
//       * L1(t) reads h0[t&1] written by L0(t) pre-Bar(t) ✓.
//   - x-staging LDS is gone -> x loaded per-wave directly from global
//     (R1's verified issue_x/cvt_x), issued at L0 start, consumed after the
//     32 whh0 MFMAs (latency cover).  Transient regs only (no cross-barrier
//     persistence = not R1's spill trap).
//   - h1 written directly after act (hb staging gone, -8 regs).
//   - L1 does reg-weight whh1 MFMAs first; the 16 wf (wih1) LDS reads queue
//     behind the 4 h1 reads and hide under those MFMAs.
// Activations use v_rcp_f32 (R7): 1-ULP rcp vs ~8-inst IEEE divide.
// ---------------------------------------------------------------------------

typedef short  short8   __attribute__((ext_vector_type(8)));
typedef float  float4_t __attribute__((ext_vector_type(4)));

#define WIH1_OFF 0        // 131072 B : w_ih1, persistent in LDS
#define H0_OFF   131072   // 2 x 8192 B : h0 double buffer
#define H1_OFF   147456   // 2 x 8192 B : h1 double buffer
#define SMEM_SZ  163840   // full 160 KiB LDS (dynamic alloc)

__device__ __forceinline__ unsigned short bf16r(float v) {
  union { float f; unsigned u; } x; x.f = v;
  unsigned r = x.u + 0x7fffu + ((x.u >> 16) & 1u);   // round-to-nearest-even
  return (unsigned short)(r >> 16);
}
__device__ __forceinline__ float bf2f(unsigned short b) {
  union { unsigned u; float f; } x; x.u = ((unsigned)b) << 16;
  return x.f;
}
// v_rcp_f32-based activations (1 ULP; negligible vs bf16 quantum).
__device__ __forceinline__ float sigf(float x) {
  return __builtin_amdgcn_rcpf(1.0f + __expf(-x));
}
__device__ __forceinline__ float tanhfast(float x) {
  return 1.0f - 2.0f * __builtin_amdgcn_rcpf(__expf(2.0f * x) + 1.0f);
}

// ---------------------------------------------------------------------------
// Prologue: pack weights (fp32 -> bf16) into MFMA B-frag tiled layout in ws.
// ws (unsigned short units):
//   [0      ,16384) : w_ih0  [1 kc][32 tiles][64 lanes][8]  (k padded to 32)
//   [16384  ,81920) : w_hh0  [4 kc][32 tiles][64][8]
//   [81920 ,147456) : w_ih1  [4 kc][32][64][8]
//   [147456,212992) : w_hh1  [4 kc][32][64][8]
// element (tile,lane,j): row = tile*16 + (lane&15), k = kc*32 + (lane>>4)*8 + j
// ---------------------------------------------------------------------------
__global__ void pack_weights(const float* __restrict__ wih0, const float* __restrict__ whh0,
                             const float* __restrict__ wih1, const float* __restrict__ whh1,
                             unsigned short* __restrict__ dst)
{
  int e = blockIdx.x * 256 + threadIdx.x;
  const float* src; int K; int i;
  if      (e < 16384)  { src = wih0; K = 28;  i = e;          }
  else if (e < 81920)  { src = whh0; K = 128; i = e - 16384;  }
  else if (e < 147456) { src = wih1; K = 128; i = e - 81920;  }
  else if (e < 212992) { src = whh1; K = 128; i = e - 147456; }
  else return;
  int j = i & 7, lane = (i >> 3) & 63, tile = (i >> 9) & 31, kc = i >> 14;
  int row = tile * 16 + (lane & 15);
  int k = kc * 32 + ((lane >> 4) << 3) + j;
  float v = (k < K) ? src[row * K + k] : 0.0f;
  dst[e] = bf16r(v);
}

// ---------------------------------------------------------------------------
// Main fused kernel.
// ---------------------------------------------------------------------------
__global__ __launch_bounds__(512, 2)
void lstm_fused(const float* __restrict__ xg,
                const unsigned short* __restrict__ wpack,
                const float* __restrict__ bih0, const float* __restrict__ bhh0,
                const float* __restrict__ bih1, const float* __restrict__ bhh1,
                const float* __restrict__ wout, const float* __restrict__ bout,
                float* __restrict__ out)
{
  extern __shared__ __align__(16) char smem[];

  const int tid  = threadIdx.x;
  const int lane = tid & 63;
  const int wave = tid >> 6;          // 0..7, owns h-dims [wave*16, wave*16+16)
  const int q    = lane >> 4;         // quad: acc rows q*4 .. q*4+3
  const int mcol = lane & 15;         // acc col = h-dim within wave slice
  const int n0   = blockIdx.x * 32;   // batch tile base

  const short8* wp = (const short8*)wpack;

  // ---- persistent weight fragments in registers --------------------------
  short8 wih0[4], whh0[4][4], whh1[4][4];          // [g] / [kc][g]
#pragma unroll
  for (int g = 0; g < 4; ++g)
    wih0[g] = wp[(g * 8 + wave) * 64 + lane];
#pragma unroll
  for (int kc = 0; kc < 4; ++kc)
#pragma unroll
    for (int g = 0; g < 4; ++g) {
      whh0[kc][g] = wp[ 2048 + (kc * 32 + g * 8 + wave) * 64 + lane];
      whh1[kc][g] = wp[18432 + (kc * 32 + g * 8 + wave) * 64 + lane];
    }

  // ---- persistent w_ih1 in LDS (131072 B) --------------------------------
  {
    short8* dstp = (short8*)smem;
#pragma unroll
    for (int rr = 0; rr < 16; ++rr)
      dstp[rr * 512 + tid] = wp[10240 + rr * 512 + tid];
  }

  // ---- biases (per-lane, gate g, dim = wave*16+mcol) ---------------------
  float bias0[4], bias1[4];
  {
    const int d = wave * 16 + mcol;
#pragma unroll
    for (int g = 0; g < 4; ++g) {
      bias0[g] = bih0[g * 128 + d] + bhh0[g * 128 + d];
      bias1[g] = bih1[g * 128 + d] + bhh1[g * 128 + d];
    }
  }

  // ---- zero the "B" halves of h0/h1 (read as h_{-1} at t=0) --------------
  {
    int* z0 = (int*)(smem + H0_OFF + 8192);
    int* z1 = (int*)(smem + H1_OFF + 8192);
#pragma unroll
    for (int rr = 0; rr < 4; ++rr) { z0[rr * 512 + tid] = 0; z1[rr * 512 + tid] = 0; }
  }

  __syncthreads();   // wih1 in LDS + h zeros visible

  const short8* W1f = (const short8*)(smem + WIH1_OFF);

  // per-lane constant part of the h-write address (A-frag tiled position of
  // element (s, d) with d = wave*16+mcol):
  const int kc_d   = wave >> 1;
  const int sub    = ((wave & 1) << 1) | (mcol >> 3);
  const int hconst = kc_d * 1024 + sub * 256 + q * 64 + (mcol & 7) * 2;

  int h0r = H0_OFF + 8192, h0w = H0_OFF;   // t=0: read zeros (buf1), write buf0
  int h1r = H1_OFF + 8192, h1w = H1_OFF;

  float c0[2][4] = {{0.f,0.f,0.f,0.f},{0.f,0.f,0.f,0.f}};
  float c1[2][4] = {{0.f,0.f,0.f,0.f},{0.f,0.f,0.f,0.f}};

#pragma unroll 1
  for (int t = 0; t < 28; ++t) {
    float4_t acc[2][4];

    // ---- issue x_t global loads NOW (covered by the 32 whh0 MFMAs) ------
    // lane needs x[n0 + mt*16 + mcol][t*28 + q*8 + j], j=0..7 (k pad -> 0).
    float4_t xa[2], xb[2];
#pragma unroll
    for (int mt = 0; mt < 2; ++mt) {
      const float* xsrc = xg + (size_t)(n0 + mt * 16 + mcol) * 784 + t * 28 + q * 8;
      xa[mt] = *(const float4_t*)xsrc;
      // q==3: only k=24..27 valid; clamp addr (stay in-bounds), zero after.
      const float* x2 = xsrc + ((q == 3) ? 0 : 4);
      float4_t v = *(const float4_t*)x2;
      if (q == 3) v = (float4_t){0.f, 0.f, 0.f, 0.f};
      xb[mt] = v;
    }

    // ================= LAYER 0 : gates = b0 + h0@Whh0^T + x_t@Wih0^T =====
#pragma unroll
    for (int mt = 0; mt < 2; ++mt)
#pragma unroll
      for (int g = 0; g < 4; ++g)
        acc[mt][g] = (float4_t){bias0[g], bias0[g], bias0[g], bias0[g]};
    {
      const short8* H0R = (const short8*)(smem + h0r);
#pragma unroll
      for (int kc = 0; kc < 4; ++kc)
#pragma unroll
        for (int mt = 0; mt < 2; ++mt) {
          short8 hf = H0R[(mt * 4 + kc) * 64 + lane];
#pragma unroll
          for (int g = 0; g < 4; ++g)
            acc[mt][g] = __builtin_amdgcn_mfma_f32_16x16x32_bf16(hf, whh0[kc][g], acc[mt][g], 0, 0, 0);
        }
    }
    // convert x (waits on the global loads; they had the whh0 phase to land)
#pragma unroll
    for (int mt = 0; mt < 2; ++mt) {
      short8 f;
#pragma unroll
      for (int j = 0; j < 4; ++j) {
        f[j]     = (short)bf16r(xa[mt][j]);
        f[j + 4] = (short)bf16r(xb[mt][j]);
      }
#pragma unroll
      for (int g = 0; g < 4; ++g)
        acc[mt][g] = __builtin_amdgcn_mfma_f32_16x16x32_bf16(f, wih0[g], acc[mt][g], 0, 0, 0);
    }
    // activations (gate order i,f,g,o); c stays in registers.  h0_t written
    // DIRECTLY to buf[t&1]: previous readers (L1(t-1), L0(t)) of that buffer
    // ran in earlier barrier intervals -> no pre-write barrier needed.
#pragma unroll
    for (int mt = 0; mt < 2; ++mt)
#pragma unroll
      for (int r = 0; r < 4; ++r) {
        float c = sigf(acc[mt][1][r]) * c0[mt][r] + sigf(acc[mt][0][r]) * tanhfast(acc[mt][2][r]);
        c0[mt][r] = c;
        *(unsigned short*)(smem + h0w + mt * 4096 + r * 16 + hconst) =
            bf16r(sigf(acc[mt][3][r]) * tanhfast(c));
      }

    __syncthreads();   // THE barrier: h0_t and h1_{t-1} visible

    // ================= LAYER 1 : gates = b1 + h1@Whh1^T + h0_t@Wih1^T ====
#pragma unroll
    for (int mt = 0; mt < 2; ++mt)
#pragma unroll
      for (int g = 0; g < 4; ++g)
        acc[mt][g] = (float4_t){bias1[g], bias1[g], bias1[g], bias1[g]};
    {
      // reg-weight whh1 MFMAs first: their 8 LDS reads return ahead of the
      // 16 wf reads (FIFO), and the MFMAs hide the wf latency.
      const short8* H1R = (const short8*)(smem + h1r);
#pragma unroll
      for (int kc = 0; kc < 4; ++kc)
#pragma unroll
        for (int mt = 0; mt < 2; ++mt) {
          short8 hf = H1R[(mt * 4 + kc) * 64 + lane];
#pragma unroll
          for (int g = 0; g < 4; ++g)
            acc[mt][g] = __builtin_amdgcn_mfma_f32_16x16x32_bf16(hf, whh1[kc][g], acc[mt][g], 0, 0, 0);
        }
      const short8* H0W = (const short8*)(smem + h0w);
#pragma unroll
      for (int kc = 0; kc < 4; ++kc) {
        short8 wf[4];
#pragma unroll
        for (int g = 0; g < 4; ++g)
          wf[g] = W1f[(kc * 32 + g * 8 + wave) * 64 + lane];
#pragma unroll
        for (int mt = 0; mt < 2; ++mt) {
          short8 hf = H0W[(mt * 4 + kc) * 64 + lane];
#pragma unroll
          for (int g = 0; g < 4; ++g)
            acc[mt][g] = __builtin_amdgcn_mfma_f32_16x16x32_bf16(hf, wf[g], acc[mt][g], 0, 0, 0);
        }
      }
    }
    // activations; h1_t written DIRECTLY to buf[t&1] (previous reader
    // L1(t-1) ran before Bar(t); visibility for L1(t+1) via Bar(t+1)).
#pragma unroll
    for (int mt = 0; mt < 2; ++mt)
#pragma unroll
      for (int r = 0; r < 4; ++r) {
        float c = sigf(acc[mt][1][r]) * c1[mt][r] + sigf(acc[mt][0][r]) * tanhfast(acc[mt][2][r]);
        c1[mt][r] = c;
        *(unsigned short*)(smem + h1w + mt * 4096 + r * 16 + hconst) =
            bf16r(sigf(acc[mt][3][r]) * tanhfast(c));
      }

    h0r ^= 8192; h0w ^= 8192; h1r ^= 8192; h1w ^= 8192;
  }
  __syncthreads();     // final h1 (buf1: t=27 wrote H1_OFF+8192) visible

  // ================= epilogue: out[s][o] = h1 . wout[o] + bout[o] =========
  if (tid < 320) {
    const short8* H1f = (const short8*)(smem + H1_OFF + 8192);
    int s = tid / 10, o = tid - (tid / 10) * 10;
    float sum = bout[o];
#pragma unroll
    for (int kc = 0; kc < 4; ++kc)
#pragma unroll
      for (int sb = 0; sb < 4; ++sb) {
        short8 hv = H1f[((s >> 4) * 4 + kc) * 64 + sb * 16 + (s & 15)];
        int dbase = kc * 32 + sb * 8;
        float4_t w0 = *(const float4_t*)(wout + o * 128 + dbase);
        float4_t w1 = *(const float4_t*)(wout + o * 128 + dbase + 4);
#pragma unroll
        for (int j = 0; j < 4; ++j) {
          sum += bf2f((unsigned short)hv[j])     * w0[j];
          sum += bf2f((unsigned short)hv[j + 4]) * w1[j];
        }
      }
    out[(size_t)(n0 + s) * 10 + o] = sum;
  }
}

extern "C" void kernel_launch(void* const* d_in, const int* in_sizes, int n_in,
                              void* d_out, int out_size, void* d_ws, size_t ws_size,
                              hipStream_t stream) {
  const float* x    = (const float*)d_in[0];
  const float* wih0 = (const float*)d_in[1];
  const float* whh0 = (const float*)d_in[2];
  const float* bih0 = (const float*)d_in[3];
  const float* bhh0 = (const float*)d_in[4];
  const float* wih1 = (const float*)d_in[5];
  const float* whh1 = (const float*)d_in[6];
  const float* bih1 = (const float*)d_in[7];
  const float* bhh1 = (const float*)d_in[8];
  const float* wout = (const float*)d_in[9];
  const float* bout = (const float*)d_in[10];

  unsigned short* wp = (unsigned short*)d_ws;   // 425984 B used

  pack_weights<<<832, 256, 0, stream>>>(wih0, whh0, wih1, whh1, wp);
  lstm_fused<<<256, 512, SMEM_SZ, stream>>>(x, wp, bih0, bhh0, bih1, bhh1, wout, bout,
                                            (float*)d_out);
}